// Round 1
// baseline (509.274 us; speedup 1.0000x reference)
//
#include <hip/hip_runtime.h>

#define SCAN_BS 512

// ---------- CSR build ----------

__global__ __launch_bounds__(256) void zero_ints(int* p, int n) {
  int i = blockIdx.x * 256 + threadIdx.x;
  if (i < n) p[i] = 0;
}

__global__ __launch_bounds__(256) void count_deg(const int* __restrict__ src,
                                                 const int* __restrict__ dst,
                                                 int* deg_out, int* deg_in, int e) {
  int i = blockIdx.x * 256 + threadIdx.x;
  if (i < e) {
    atomicAdd(&deg_out[src[i]], 1);
    atomicAdd(&deg_in[dst[i]], 1);
  }
}

__global__ __launch_bounds__(SCAN_BS) void block_sums(const int* __restrict__ deg,
                                                      int* bsum, int n) {
  __shared__ int s[SCAN_BS];
  int i = blockIdx.x * SCAN_BS + threadIdx.x;
  s[threadIdx.x] = (i < n) ? deg[i] : 0;
  __syncthreads();
  for (int off = SCAN_BS / 2; off > 0; off >>= 1) {
    if (threadIdx.x < off) s[threadIdx.x] += s[threadIdx.x + off];
    __syncthreads();
  }
  if (threadIdx.x == 0) bsum[blockIdx.x] = s[0];
}

__global__ void scan_bsums(int* bsum, int nb) {
  if (threadIdx.x == 0 && blockIdx.x == 0) {
    int run = 0;
    for (int b = 0; b < nb; b++) { int t = bsum[b]; bsum[b] = run; run += t; }
  }
}

__global__ __launch_bounds__(SCAN_BS) void scan_block(const int* __restrict__ deg,
                                                      const int* __restrict__ bsum,
                                                      int* row_start, int n, int e_total) {
  __shared__ int s[SCAN_BS];
  int i = blockIdx.x * SCAN_BS + threadIdx.x;
  int v = (i < n) ? deg[i] : 0;
  s[threadIdx.x] = v;
  __syncthreads();
  for (int off = 1; off < SCAN_BS; off *= 2) {
    int t = (threadIdx.x >= (unsigned)off) ? s[threadIdx.x - off] : 0;
    __syncthreads();
    s[threadIdx.x] += t;
    __syncthreads();
  }
  if (i < n) row_start[i] = (s[threadIdx.x] - v) + bsum[blockIdx.x];
  if (i == n - 1) row_start[n] = e_total;
}

__global__ __launch_bounds__(256) void fill_csr(const int* __restrict__ src,
                                                const int* __restrict__ dst,
                                                const int* __restrict__ row_start,
                                                int* cursor, int* csr_src, int e) {
  int i = blockIdx.x * 256 + threadIdx.x;
  if (i < e) {
    int d = dst[i];
    int pos = row_start[d] + atomicAdd(&cursor[d], 1);
    csr_src[pos] = src[i];
  }
}

__global__ __launch_bounds__(256) void compute_inv(const int* __restrict__ deg_out,
                                                   const int* __restrict__ deg_in,
                                                   float* inv_out, float* inv_in, int n) {
  int i = blockIdx.x * 256 + threadIdx.x;
  if (i < n) {
    int a = deg_out[i]; if (a < 1) a = 1;
    int b = deg_in[i];  if (b < 1) b = 1;
    inv_out[i] = rsqrtf((float)a);
    inv_in[i]  = rsqrtf((float)b);
  }
}

// ---------- SpMM: agg[i,:] = inv_in[i] * sum_{e: dst=i} inv_out[src] * x[src,:] ----------
// one wave (64 lanes) per dst row; lane holds 2 floats (float2 = 8B/lane, 512B/row)

__global__ __launch_bounds__(256) void spmm(const float* __restrict__ x,
                                            const int* __restrict__ row_start,
                                            const int* __restrict__ csr_src,
                                            const float* __restrict__ inv_out,
                                            const float* __restrict__ inv_in,
                                            float* __restrict__ agg, int n) {
  int row = blockIdx.x * 4 + (threadIdx.x >> 6);
  if (row >= n) return;
  int lane = threadIdx.x & 63;
  int e0 = row_start[row];
  int e1 = row_start[row + 1];
  float ax = 0.f, ay = 0.f;
  for (int e = e0; e < e1; e++) {
    int s = csr_src[e];
    float sc = inv_out[s];
    float2 v = *(const float2*)&x[(size_t)s * 128 + lane * 2];
    ax += v.x * sc;
    ay += v.y * sc;
  }
  float si = inv_in[row];
  float2 o; o.x = ax * si; o.y = ay * si;
  *(float2*)&agg[(size_t)row * 128 + lane * 2] = o;
}

// ---------- GEMM + bias + ReLU: out = relu(A @ W + b), A:[n,128], W:[128,128] ----------
// block: 32 rows x 128 cols, 256 threads, 4x4 micro-tile per thread.
// A tile staged transposed in LDS: Ast[k][r], row-pad 36 floats (keeps 16B align for b128).

__global__ __launch_bounds__(256) void gemm_bias_relu(const float* __restrict__ A,
                                                      const float* __restrict__ W,
                                                      const float* __restrict__ bias,
                                                      float* __restrict__ out, int n) {
  __shared__ float Ast[128 * 36];
  const int t = threadIdx.x;
  const int blockRow = blockIdx.x * 32;

  // stage 32x128 A-tile transposed: thread loads 4 float4s (coalesced rows)
  {
    int lr = t >> 5;            // 0..7
    int lk = (t & 31) * 4;      // 0..124
    for (int rr = lr; rr < 32; rr += 8) {
      int r = blockRow + rr;
      float4 v = make_float4(0.f, 0.f, 0.f, 0.f);
      if (r < n) v = *(const float4*)&A[(size_t)r * 128 + lk];
      Ast[(lk + 0) * 36 + rr] = v.x;
      Ast[(lk + 1) * 36 + rr] = v.y;
      Ast[(lk + 2) * 36 + rr] = v.z;
      Ast[(lk + 3) * 36 + rr] = v.w;
    }
  }
  __syncthreads();

  const int tx = t & 31;        // col group
  const int ty = t >> 5;        // row group
  const int c = tx * 4;         // cols c..c+3
  const int rb = ty * 4;        // local rows rb..rb+3

  float acc[4][4] = {};
#pragma unroll 4
  for (int k = 0; k < 128; k++) {
    float4 a4 = *(const float4*)&Ast[k * 36 + rb];            // rows rb..rb+3 (2-addr broadcast)
    float4 w4 = *(const float4*)&W[k * 128 + c];              // L1/L2-hot
    acc[0][0] += a4.x * w4.x; acc[0][1] += a4.x * w4.y; acc[0][2] += a4.x * w4.z; acc[0][3] += a4.x * w4.w;
    acc[1][0] += a4.y * w4.x; acc[1][1] += a4.y * w4.y; acc[1][2] += a4.y * w4.z; acc[1][3] += a4.y * w4.w;
    acc[2][0] += a4.z * w4.x; acc[2][1] += a4.z * w4.y; acc[2][2] += a4.z * w4.z; acc[2][3] += a4.z * w4.w;
    acc[3][0] += a4.w * w4.x; acc[3][1] += a4.w * w4.y; acc[3][2] += a4.w * w4.z; acc[3][3] += a4.w * w4.w;
  }

  float4 b4 = *(const float4*)&bias[c];
#pragma unroll
  for (int j = 0; j < 4; j++) {
    int r = blockRow + rb + j;
    if (r < n) {
      float4 o;
      o.x = fmaxf(acc[j][0] + b4.x, 0.f);
      o.y = fmaxf(acc[j][1] + b4.y, 0.f);
      o.z = fmaxf(acc[j][2] + b4.z, 0.f);
      o.w = fmaxf(acc[j][3] + b4.w, 0.f);
      *(float4*)&out[(size_t)r * 128 + c] = o;
    }
  }
}

// ---------- launch ----------

extern "C" void kernel_launch(void* const* d_in, const int* in_sizes, int n_in,
                              void* d_out, int out_size, void* d_ws, size_t ws_size,
                              hipStream_t stream) {
  const float* x   = (const float*)d_in[0];
  const float* Ws  = (const float*)d_in[1];
  const float* bs  = (const float*)d_in[2];
  const int* esrc  = (const int*)d_in[3];
  const int* edst  = (const int*)d_in[4];

  const int D = 128;
  const int N = in_sizes[0] / D;
  const int E = in_sizes[3];
  const int L = in_sizes[1] / (D * D);
  const int nb = (N + SCAN_BS - 1) / SCAN_BS;

  // workspace layout (4B units)
  int* w = (int*)d_ws;
  int* deg_out   = w;  w += N;
  int* deg_in    = w;  w += N;
  int* cursor    = w;  w += N;
  int* row_start = w;  w += N + 1;
  int* bsum      = w;  w += ((nb + 63) / 64) * 64;
  int* csr_src   = w;  w += E;
  float* inv_out = (float*)w;  w += N;
  float* inv_in  = (float*)w;  w += N;
  size_t ofs = (size_t)(w - (int*)d_ws);
  ofs = (ofs + 3) & ~(size_t)3;          // 16B align for float4
  float* agg  = (float*)d_ws + ofs;
  float* xbuf = agg + (size_t)N * D;

  zero_ints<<<dim3((3 * N + 255) / 256), dim3(256), 0, stream>>>(deg_out, 3 * N);
  count_deg<<<dim3((E + 255) / 256), dim3(256), 0, stream>>>(esrc, edst, deg_out, deg_in, E);
  block_sums<<<dim3(nb), dim3(SCAN_BS), 0, stream>>>(deg_in, bsum, N);
  scan_bsums<<<dim3(1), dim3(64), 0, stream>>>(bsum, nb);
  scan_block<<<dim3(nb), dim3(SCAN_BS), 0, stream>>>(deg_in, bsum, row_start, N, E);
  fill_csr<<<dim3((E + 255) / 256), dim3(256), 0, stream>>>(esrc, edst, row_start, cursor, csr_src, E);
  compute_inv<<<dim3((N + 255) / 256), dim3(256), 0, stream>>>(deg_out, deg_in, inv_out, inv_in, N);

  const float* xc = x;
  float* outf = (float*)d_out;
  for (int l = 0; l < L; l++) {
    spmm<<<dim3((N + 3) / 4), dim3(256), 0, stream>>>(xc, row_start, csr_src, inv_out, inv_in, agg, N);
    float* o = (l == L - 1) ? outf : xbuf;
    gemm_bias_relu<<<dim3((N + 31) / 32), dim3(256), 0, stream>>>(
        agg, Ws + (size_t)l * D * D, bs + (size_t)l * D, o, N);
    xc = xbuf;
  }
}

// Round 2
// 439.067 us; speedup vs baseline: 1.1599x; 1.1599x over previous
//
#include <hip/hip_runtime.h>

#define SCAN_BS 512

// ---------- CSR build ----------

__global__ __launch_bounds__(256) void zero_ints(int* p, int n) {
  int i = blockIdx.x * 256 + threadIdx.x;
  if (i < n) p[i] = 0;
}

__global__ __launch_bounds__(256) void count_deg(const int* __restrict__ src,
                                                 const int* __restrict__ dst,
                                                 int* deg_out, int* deg_in, int e) {
  int i = blockIdx.x * 256 + threadIdx.x;
  if (i < e) {
    atomicAdd(&deg_out[src[i]], 1);
    atomicAdd(&deg_in[dst[i]], 1);
  }
}

__global__ __launch_bounds__(SCAN_BS) void block_sums(const int* __restrict__ deg,
                                                      int* bsum, int n) {
  __shared__ int s[SCAN_BS];
  int i = blockIdx.x * SCAN_BS + threadIdx.x;
  s[threadIdx.x] = (i < n) ? deg[i] : 0;
  __syncthreads();
  for (int off = SCAN_BS / 2; off > 0; off >>= 1) {
    if (threadIdx.x < off) s[threadIdx.x] += s[threadIdx.x + off];
    __syncthreads();
  }
  if (threadIdx.x == 0) bsum[blockIdx.x] = s[0];
}

__global__ void scan_bsums(int* bsum, int nb) {
  if (threadIdx.x == 0 && blockIdx.x == 0) {
    int run = 0;
    for (int b = 0; b < nb; b++) { int t = bsum[b]; bsum[b] = run; run += t; }
  }
}

__global__ __launch_bounds__(SCAN_BS) void scan_block(const int* __restrict__ deg,
                                                      const int* __restrict__ bsum,
                                                      int* row_start, int n, int e_total) {
  __shared__ int s[SCAN_BS];
  int i = blockIdx.x * SCAN_BS + threadIdx.x;
  int v = (i < n) ? deg[i] : 0;
  s[threadIdx.x] = v;
  __syncthreads();
  for (int off = 1; off < SCAN_BS; off *= 2) {
    int t = (threadIdx.x >= (unsigned)off) ? s[threadIdx.x - off] : 0;
    __syncthreads();
    s[threadIdx.x] += t;
    __syncthreads();
  }
  if (i < n) row_start[i] = (s[threadIdx.x] - v) + bsum[blockIdx.x];
  if (i == n - 1) row_start[n] = e_total;
}

__global__ __launch_bounds__(256) void fill_csr(const int* __restrict__ src,
                                                const int* __restrict__ dst,
                                                const int* __restrict__ row_start,
                                                int* cursor, int* csr_src, int e) {
  int i = blockIdx.x * 256 + threadIdx.x;
  if (i < e) {
    int d = dst[i];
    int pos = row_start[d] + atomicAdd(&cursor[d], 1);
    csr_src[pos] = src[i];
  }
}

__global__ __launch_bounds__(256) void compute_inv(const int* __restrict__ deg_out,
                                                   const int* __restrict__ deg_in,
                                                   float* inv_out, float* inv_in, int n) {
  int i = blockIdx.x * 256 + threadIdx.x;
  if (i < n) {
    int a = deg_out[i]; if (a < 1) a = 1;
    int b = deg_in[i];  if (b < 1) b = 1;
    inv_out[i] = rsqrtf((float)a);
    inv_in[i]  = rsqrtf((float)b);
  }
}

// ---------- SpMM variants ----------
// one wave per dst row, lane holds float2 (512B/row coalesced).
// 4x edge unroll -> 4 independent row gathers in flight per wave.

// layer 0: applies inv_out[src] per edge (x is the raw input)
__global__ __launch_bounds__(256) void spmm_scaled(const float* __restrict__ x,
                                                   const int* __restrict__ row_start,
                                                   const int* __restrict__ csr_src,
                                                   const float* __restrict__ inv_out,
                                                   const float* __restrict__ inv_in,
                                                   float* __restrict__ agg, int n) {
  int row = blockIdx.x * 4 + (threadIdx.x >> 6);
  if (row >= n) return;
  int lane2 = (threadIdx.x & 63) * 2;
  int e0 = row_start[row];
  int e1 = row_start[row + 1];
  float ax = 0.f, ay = 0.f;
  int e = e0;
  for (; e + 4 <= e1; e += 4) {
    int s0 = csr_src[e + 0];
    int s1 = csr_src[e + 1];
    int s2 = csr_src[e + 2];
    int s3 = csr_src[e + 3];
    float c0 = inv_out[s0], c1 = inv_out[s1], c2 = inv_out[s2], c3 = inv_out[s3];
    float2 v0 = *(const float2*)&x[(size_t)s0 * 128 + lane2];
    float2 v1 = *(const float2*)&x[(size_t)s1 * 128 + lane2];
    float2 v2 = *(const float2*)&x[(size_t)s2 * 128 + lane2];
    float2 v3 = *(const float2*)&x[(size_t)s3 * 128 + lane2];
    ax += c0 * v0.x; ay += c0 * v0.y;
    ax += c1 * v1.x; ay += c1 * v1.y;
    ax += c2 * v2.x; ay += c2 * v2.y;
    ax += c3 * v3.x; ay += c3 * v3.y;
  }
  for (; e < e1; e++) {
    int s = csr_src[e];
    float c = inv_out[s];
    float2 v = *(const float2*)&x[(size_t)s * 128 + lane2];
    ax += c * v.x; ay += c * v.y;
  }
  float si = inv_in[row];
  float2 o; o.x = ax * si; o.y = ay * si;
  *(float2*)&agg[(size_t)row * 128 + lane2] = o;
}

// layers 1..: src normalization already folded into x by the previous GEMM epilogue
__global__ __launch_bounds__(256) void spmm_plain(const float* __restrict__ x,
                                                  const int* __restrict__ row_start,
                                                  const int* __restrict__ csr_src,
                                                  const float* __restrict__ inv_in,
                                                  float* __restrict__ agg, int n) {
  int row = blockIdx.x * 4 + (threadIdx.x >> 6);
  if (row >= n) return;
  int lane2 = (threadIdx.x & 63) * 2;
  int e0 = row_start[row];
  int e1 = row_start[row + 1];
  float ax = 0.f, ay = 0.f;
  int e = e0;
  for (; e + 4 <= e1; e += 4) {
    int s0 = csr_src[e + 0];
    int s1 = csr_src[e + 1];
    int s2 = csr_src[e + 2];
    int s3 = csr_src[e + 3];
    float2 v0 = *(const float2*)&x[(size_t)s0 * 128 + lane2];
    float2 v1 = *(const float2*)&x[(size_t)s1 * 128 + lane2];
    float2 v2 = *(const float2*)&x[(size_t)s2 * 128 + lane2];
    float2 v3 = *(const float2*)&x[(size_t)s3 * 128 + lane2];
    ax += v0.x + v1.x + v2.x + v3.x;
    ay += v0.y + v1.y + v2.y + v3.y;
  }
  for (; e < e1; e++) {
    int s = csr_src[e];
    float2 v = *(const float2*)&x[(size_t)s * 128 + lane2];
    ax += v.x; ay += v.y;
  }
  float si = inv_in[row];
  float2 o; o.x = ax * si; o.y = ay * si;
  *(float2*)&agg[(size_t)row * 128 + lane2] = o;
}

// ---------- GEMM + bias + ReLU (+ optional row scale for next layer's src-norm) ----------
// block: 32 rows x 128 cols, 256 threads, 4x4 micro-tile.
// A staged UNtransposed in LDS [32][132]: b128 writes (4-way, ~free),
// k-loop reads are 2-distinct-address b32 broadcasts (conflict-free).

__global__ __launch_bounds__(256) void gemm_bias_relu(const float* __restrict__ A,
                                                      const float* __restrict__ W,
                                                      const float* __restrict__ bias,
                                                      const float* __restrict__ rowscale,
                                                      float* __restrict__ out, int n) {
  __shared__ float Ast[32 * 132];
  const int t = threadIdx.x;
  const int blockRow = blockIdx.x * 32;

  {
    int lr = t >> 5;            // 0..7
    int lk = (t & 31) * 4;      // 0..124
    for (int rr = lr; rr < 32; rr += 8) {
      int r = blockRow + rr;
      float4 v = make_float4(0.f, 0.f, 0.f, 0.f);
      if (r < n) v = *(const float4*)&A[(size_t)r * 128 + lk];
      *(float4*)&Ast[rr * 132 + lk] = v;
    }
  }
  __syncthreads();

  const int tx = t & 31;
  const int ty = t >> 5;
  const int c = tx * 4;
  const int rb = ty * 4;

  float acc[4][4] = {};
#pragma unroll 4
  for (int k = 0; k < 128; k++) {
    float a0 = Ast[(rb + 0) * 132 + k];
    float a1 = Ast[(rb + 1) * 132 + k];
    float a2 = Ast[(rb + 2) * 132 + k];
    float a3 = Ast[(rb + 3) * 132 + k];
    float4 w4 = *(const float4*)&W[k * 128 + c];
    acc[0][0] += a0 * w4.x; acc[0][1] += a0 * w4.y; acc[0][2] += a0 * w4.z; acc[0][3] += a0 * w4.w;
    acc[1][0] += a1 * w4.x; acc[1][1] += a1 * w4.y; acc[1][2] += a1 * w4.z; acc[1][3] += a1 * w4.w;
    acc[2][0] += a2 * w4.x; acc[2][1] += a2 * w4.y; acc[2][2] += a2 * w4.z; acc[2][3] += a2 * w4.w;
    acc[3][0] += a3 * w4.x; acc[3][1] += a3 * w4.y; acc[3][2] += a3 * w4.z; acc[3][3] += a3 * w4.w;
  }

  float4 b4 = *(const float4*)&bias[c];
#pragma unroll
  for (int j = 0; j < 4; j++) {
    int r = blockRow + rb + j;
    if (r < n) {
      float s = rowscale ? rowscale[r] : 1.0f;
      float4 o;
      o.x = fmaxf(acc[j][0] + b4.x, 0.f) * s;
      o.y = fmaxf(acc[j][1] + b4.y, 0.f) * s;
      o.z = fmaxf(acc[j][2] + b4.z, 0.f) * s;
      o.w = fmaxf(acc[j][3] + b4.w, 0.f) * s;
      *(float4*)&out[(size_t)r * 128 + c] = o;
    }
  }
}

// ---------- launch ----------

extern "C" void kernel_launch(void* const* d_in, const int* in_sizes, int n_in,
                              void* d_out, int out_size, void* d_ws, size_t ws_size,
                              hipStream_t stream) {
  const float* x   = (const float*)d_in[0];
  const float* Ws  = (const float*)d_in[1];
  const float* bs  = (const float*)d_in[2];
  const int* esrc  = (const int*)d_in[3];
  const int* edst  = (const int*)d_in[4];

  const int D = 128;
  const int N = in_sizes[0] / D;
  const int E = in_sizes[3];
  const int L = in_sizes[1] / (D * D);
  const int nb = (N + SCAN_BS - 1) / SCAN_BS;

  // workspace layout (4B units)
  int* w = (int*)d_ws;
  int* deg_out   = w;  w += N;
  int* deg_in    = w;  w += N;
  int* cursor    = w;  w += N;
  int* row_start = w;  w += N + 1;
  int* bsum      = w;  w += ((nb + 63) / 64) * 64;
  int* csr_src   = w;  w += E;
  float* inv_out = (float*)w;  w += N;
  float* inv_in  = (float*)w;  w += N;
  size_t ofs = (size_t)(w - (int*)d_ws);
  ofs = (ofs + 3) & ~(size_t)3;          // 16B align for float4
  float* agg  = (float*)d_ws + ofs;
  float* xbuf = agg + (size_t)N * D;

  zero_ints<<<dim3((3 * N + 255) / 256), dim3(256), 0, stream>>>(deg_out, 3 * N);
  count_deg<<<dim3((E + 255) / 256), dim3(256), 0, stream>>>(esrc, edst, deg_out, deg_in, E);
  block_sums<<<dim3(nb), dim3(SCAN_BS), 0, stream>>>(deg_in, bsum, N);
  scan_bsums<<<dim3(1), dim3(64), 0, stream>>>(bsum, nb);
  scan_block<<<dim3(nb), dim3(SCAN_BS), 0, stream>>>(deg_in, bsum, row_start, N, E);
  fill_csr<<<dim3((E + 255) / 256), dim3(256), 0, stream>>>(esrc, edst, row_start, cursor, csr_src, E);
  compute_inv<<<dim3((N + 255) / 256), dim3(256), 0, stream>>>(deg_out, deg_in, inv_out, inv_in, N);

  float* outf = (float*)d_out;
  const dim3 sgrid((N + 3) / 4), sblk(256);
  const dim3 ggrid((N + 31) / 32), gblk(256);

  // layer 0: raw x with per-edge src scale; epilogue folds inv_out for layer 1
  spmm_scaled<<<sgrid, sblk, 0, stream>>>(x, row_start, csr_src, inv_out, inv_in, agg, N);
  gemm_bias_relu<<<ggrid, gblk, 0, stream>>>(agg, Ws, bs, (L > 1) ? inv_out : nullptr,
                                             (L == 1) ? outf : xbuf, N);
  // middle layers
  for (int l = 1; l < L - 1; l++) {
    spmm_plain<<<sgrid, sblk, 0, stream>>>(xbuf, row_start, csr_src, inv_in, agg, N);
    gemm_bias_relu<<<ggrid, gblk, 0, stream>>>(agg, Ws + (size_t)l * D * D, bs + (size_t)l * D,
                                               inv_out, xbuf, N);
  }
  // last layer: no rowscale, write d_out
  if (L > 1) {
    spmm_plain<<<sgrid, sblk, 0, stream>>>(xbuf, row_start, csr_src, inv_in, agg, N);
    gemm_bias_relu<<<ggrid, gblk, 0, stream>>>(agg, Ws + (size_t)(L - 1) * D * D,
                                               bs + (size_t)(L - 1) * D, nullptr, outf, N);
  }
}

// Round 4
// 362.857 us; speedup vs baseline: 1.4035x; 1.2100x over previous
//
#include <hip/hip_runtime.h>
#include <hip/hip_fp16.h>

typedef __attribute__((ext_vector_type(8))) short short8;
typedef __attribute__((ext_vector_type(4))) float f32x4;
typedef unsigned short u16;
typedef unsigned int u32;

#define SCAN_BS 512

// ---------- CSR build ----------

__global__ __launch_bounds__(256) void zero_ints(int* p, int n) {
  int i = blockIdx.x * 256 + threadIdx.x;
  if (i < n) p[i] = 0;
}

__global__ __launch_bounds__(256) void count_deg(const int* __restrict__ src,
                                                 const int* __restrict__ dst,
                                                 int* deg_out, int* deg_in, int e) {
  int i = blockIdx.x * 256 + threadIdx.x;
  if (i < e) {
    atomicAdd(&deg_out[src[i]], 1);
    atomicAdd(&deg_in[dst[i]], 1);
  }
}

__global__ __launch_bounds__(SCAN_BS) void block_sums(const int* __restrict__ deg,
                                                      int* bsum, int n) {
  __shared__ int s[SCAN_BS];
  int i = blockIdx.x * SCAN_BS + threadIdx.x;
  s[threadIdx.x] = (i < n) ? deg[i] : 0;
  __syncthreads();
  for (int off = SCAN_BS / 2; off > 0; off >>= 1) {
    if (threadIdx.x < off) s[threadIdx.x] += s[threadIdx.x + off];
    __syncthreads();
  }
  if (threadIdx.x == 0) bsum[blockIdx.x] = s[0];
}

__global__ void scan_bsums(int* bsum, int nb) {
  if (threadIdx.x == 0 && blockIdx.x == 0) {
    int run = 0;
    for (int b = 0; b < nb; b++) { int t = bsum[b]; bsum[b] = run; run += t; }
  }
}

__global__ __launch_bounds__(SCAN_BS) void scan_block(const int* __restrict__ deg,
                                                      const int* __restrict__ bsum,
                                                      int* row_start, int n, int e_total) {
  __shared__ int s[SCAN_BS];
  int i = blockIdx.x * SCAN_BS + threadIdx.x;
  int v = (i < n) ? deg[i] : 0;
  s[threadIdx.x] = v;
  __syncthreads();
  for (int off = 1; off < SCAN_BS; off *= 2) {
    int t = (threadIdx.x >= (unsigned)off) ? s[threadIdx.x - off] : 0;
    __syncthreads();
    s[threadIdx.x] += t;
    __syncthreads();
  }
  if (i < n) row_start[i] = (s[threadIdx.x] - v) + bsum[blockIdx.x];
  if (i == n - 1) row_start[n] = e_total;
}

__global__ __launch_bounds__(256) void fill_csr(const int* __restrict__ src,
                                                const int* __restrict__ dst,
                                                const int* __restrict__ row_start,
                                                int* cursor, int* csr_src, int e) {
  int i = blockIdx.x * 256 + threadIdx.x;
  if (i < e) {
    int d = dst[i];
    int pos = row_start[d] + atomicAdd(&cursor[d], 1);
    csr_src[pos] = src[i];
  }
}

__global__ __launch_bounds__(256) void compute_inv(const int* __restrict__ deg_out,
                                                   const int* __restrict__ deg_in,
                                                   float* inv_out, float* inv_in, int n) {
  int i = blockIdx.x * 256 + threadIdx.x;
  if (i < n) {
    int a = deg_out[i]; if (a < 1) a = 1;
    int b = deg_in[i];  if (b < 1) b = 1;
    inv_out[i] = rsqrtf((float)a);
    inv_in[i]  = rsqrtf((float)b);
  }
}

// ---------- x -> fp16 with src-norm folded in: xh[i,:] = (half)(x[i,:] * inv_out[i]) ----------

__global__ __launch_bounds__(256) void x_scale_half(const float* __restrict__ x,
                                                    const float* __restrict__ inv_out,
                                                    __half2* __restrict__ xh, int n) {
  int gid = blockIdx.x * 256 + threadIdx.x;
  if (gid >= n * 64) return;
  int row = gid >> 6;
  float s = inv_out[row];
  float2 v = ((const float2*)x)[gid];
  xh[gid] = __floats2half2_rn(v.x * s, v.y * s);
}

// ---------- pack W (per layer) into MFMA B-fragment order, split hi/lo bf16 ----------
// frag element j of (layer,ntile,kstep,lane) = W[k = kstep*32+(lane>>4)*8+j][n = ntile*16+(lane&15)]

__global__ __launch_bounds__(256) void pack_W(const float* __restrict__ Ws,
                                              u16* __restrict__ Whi, u16* __restrict__ Wlo,
                                              int total) {
  int idx = blockIdx.x * 256 + threadIdx.x;
  if (idx >= total) return;
  int lane  = idx & 63;
  int kstep = (idx >> 6) & 3;
  int ntile = (idx >> 8) & 7;
  int layer = idx >> 11;
  int n  = ntile * 16 + (lane & 15);
  int k0 = kstep * 32 + (lane >> 4) * 8;
  const float* W = Ws + (size_t)layer * 128 * 128;
  size_t base = (size_t)idx * 8;
  for (int j = 0; j < 8; j++) {
    float v = W[(k0 + j) * 128 + n];
    u32 b = __float_as_uint(v);
    u32 hb = b & 0xFFFF0000u;
    float lo = v - __uint_as_float(hb);
    Whi[base + j] = (u16)(b >> 16);
    Wlo[base + j] = (u16)(__float_as_uint(lo) >> 16);
  }
}

// ---------- SpMM: agg[i,:] = inv_in[i] * sum_{e: dst=i} xh[src,:]  (src-norm pre-folded) ----------
// one wave per dst row, lane holds half2 (4B/lane, 256B/row); 4x edge unroll for MLP.
// epilogue writes agg as exact split hi/lo bf16 (GEMM A operand).

__global__ __launch_bounds__(256) void spmm_half(const __half2* __restrict__ xh,
                                                 const int* __restrict__ row_start,
                                                 const int* __restrict__ csr_src,
                                                 const float* __restrict__ inv_in,
                                                 u32* __restrict__ agg_hi,
                                                 u32* __restrict__ agg_lo, int n) {
  int row = blockIdx.x * 4 + (threadIdx.x >> 6);
  if (row >= n) return;
  int lane = threadIdx.x & 63;
  int e0 = row_start[row];
  int e1 = row_start[row + 1];
  float ax = 0.f, ay = 0.f;
  int e = e0;
  for (; e + 4 <= e1; e += 4) {
    int s0 = csr_src[e + 0];
    int s1 = csr_src[e + 1];
    int s2 = csr_src[e + 2];
    int s3 = csr_src[e + 3];
    __half2 h0 = xh[(size_t)s0 * 64 + lane];
    __half2 h1 = xh[(size_t)s1 * 64 + lane];
    __half2 h2 = xh[(size_t)s2 * 64 + lane];
    __half2 h3 = xh[(size_t)s3 * 64 + lane];
    float2 v0 = __half22float2(h0);
    float2 v1 = __half22float2(h1);
    float2 v2 = __half22float2(h2);
    float2 v3 = __half22float2(h3);
    ax += v0.x + v1.x + v2.x + v3.x;
    ay += v0.y + v1.y + v2.y + v3.y;
  }
  for (; e < e1; e++) {
    int s = csr_src[e];
    float2 v = __half22float2(xh[(size_t)s * 64 + lane]);
    ax += v.x; ay += v.y;
  }
  float si = inv_in[row];
  ax *= si; ay *= si;
  // exact split into hi/lo bf16 (truncation; lo carries the remainder)
  u32 bx = __float_as_uint(ax), by = __float_as_uint(ay);
  u32 hx = bx & 0xFFFF0000u,   hy = by & 0xFFFF0000u;
  float lx = ax - __uint_as_float(hx);
  float ly = ay - __uint_as_float(hy);
  u32 hp = (bx >> 16) | hy;
  u32 lp = (__float_as_uint(lx) >> 16) | (__float_as_uint(ly) & 0xFFFF0000u);
  size_t o = (size_t)row * 64 + lane;
  agg_hi[o] = hp;
  agg_lo[o] = lp;
}

// ---------- MFMA GEMM + bias + ReLU (+ inv_out fold into fp16 output) ----------
// block = 256 (4 waves) -> 64 rows x 128 cols. Split-bf16: hi*hi + hi*lo + lo*hi (error ~2^-16).
// W (packed, 32KB hi + 32KB lo) staged in LDS, shared by all 4 waves.

__global__ __launch_bounds__(256) void gemm_mfma(const u16* __restrict__ Ahi,
                                                 const u16* __restrict__ Alo,
                                                 const u16* __restrict__ Whi,
                                                 const u16* __restrict__ Wlo,
                                                 const float* __restrict__ bias,
                                                 const float* __restrict__ rowscale,
                                                 __half* __restrict__ out16,
                                                 float* __restrict__ out32, int n) {
  __shared__ u16 Bh[16384];  // 32 KB
  __shared__ u16 Bl[16384];  // 32 KB
  {
    uint4* dh = (uint4*)Bh; const uint4* sh = (const uint4*)Whi;
    uint4* dl = (uint4*)Bl; const uint4* sl = (const uint4*)Wlo;
    for (int i = threadIdx.x; i < 2048; i += 256) { dh[i] = sh[i]; dl[i] = sl[i]; }
  }
  __syncthreads();

  const int wave = threadIdx.x >> 6;
  const int lane = threadIdx.x & 63;
  const int quad = lane >> 4;
  const int l16  = lane & 15;
  const int rowBase = blockIdx.x * 64 + wave * 16;
  const size_t arow = (size_t)(rowBase + l16) * 128;

  f32x4 acc[8];
#pragma unroll
  for (int nt = 0; nt < 8; nt++) acc[nt] = (f32x4){0.f, 0.f, 0.f, 0.f};

#pragma unroll
  for (int ks = 0; ks < 4; ks++) {
    size_t aoff = arow + ks * 32 + quad * 8;
    short8 ahi = *(const short8*)&Ahi[aoff];
    short8 alo = *(const short8*)&Alo[aoff];
#pragma unroll
    for (int nt = 0; nt < 8; nt++) {
      int boff = ((nt * 4 + ks) * 64 + lane) * 8;
      short8 bhi = *(const short8*)&Bh[boff];
      short8 blo = *(const short8*)&Bl[boff];
      acc[nt] = __builtin_amdgcn_mfma_f32_16x16x32_bf16(ahi, bhi, acc[nt], 0, 0, 0);
      acc[nt] = __builtin_amdgcn_mfma_f32_16x16x32_bf16(ahi, blo, acc[nt], 0, 0, 0);
      acc[nt] = __builtin_amdgcn_mfma_f32_16x16x32_bf16(alo, bhi, acc[nt], 0, 0, 0);
    }
  }

  // C/D: col = lane&15 (+nt*16), row = quad*4 + reg  [m89-verified mapping]
  const int r0 = rowBase + quad * 4;
  float rs[4];
#pragma unroll
  for (int r = 0; r < 4; r++)
    rs[r] = (out16 && (r0 + r) < n) ? rowscale[r0 + r] : 1.0f;
#pragma unroll
  for (int nt = 0; nt < 8; nt++) {
    int col = nt * 16 + l16;
    float bv = bias[col];
#pragma unroll
    for (int r = 0; r < 4; r++) {
      int row = r0 + r;
      if (row < n) {
        float v = fmaxf(acc[nt][r] + bv, 0.f);
        if (out16) out16[(size_t)row * 128 + col] = __float2half(v * rs[r]);
        else       out32[(size_t)row * 128 + col] = v;
      }
    }
  }
}

// ---------- launch ----------

extern "C" void kernel_launch(void* const* d_in, const int* in_sizes, int n_in,
                              void* d_out, int out_size, void* d_ws, size_t ws_size,
                              hipStream_t stream) {
  const float* x   = (const float*)d_in[0];
  const float* Ws  = (const float*)d_in[1];
  const float* bs  = (const float*)d_in[2];
  const int* esrc  = (const int*)d_in[3];
  const int* edst  = (const int*)d_in[4];

  const int D = 128;
  const int N = in_sizes[0] / D;
  const int E = in_sizes[3];
  const int L = in_sizes[1] / (D * D);
  const int nb = (N + SCAN_BS - 1) / SCAN_BS;
  const int Npad = ((N + 63) / 64) * 64;

  // workspace layout, 256B-aligned chunks
  char* base = (char*)d_ws;
  size_t off = 0;
  auto alloc = [&](size_t bytes) {
    char* p = base + off;
    off = (off + bytes + 255) & ~(size_t)255;
    return p;
  };
  // deg_out / deg_in / cursor MUST be one contiguous block: zero_ints covers 3*N
  // (round-3 bug: per-array 256B padding left cursor's tail poisoned -> wild csr store)
  int*   deg3      = (int*)alloc((size_t)3 * N * 4);
  int*   deg_out   = deg3;
  int*   deg_in    = deg3 + N;
  int*   cursor    = deg3 + 2 * N;
  int*   row_start = (int*)alloc((size_t)(N + 1) * 4);
  int*   bsum      = (int*)alloc((size_t)nb * 4);
  int*   csr_src   = (int*)alloc((size_t)E * 4);
  float* inv_out   = (float*)alloc((size_t)N * 4);
  float* inv_in    = (float*)alloc((size_t)N * 4);
  u16*   Whi       = (u16*)alloc((size_t)L * 16384 * 2);
  u16*   Wlo       = (u16*)alloc((size_t)L * 16384 * 2);
  u16*   agg_hi    = (u16*)alloc((size_t)Npad * 128 * 2);
  u16*   agg_lo    = (u16*)alloc((size_t)Npad * 128 * 2);
  __half* xh       = (__half*)alloc((size_t)Npad * 128 * 2);

  zero_ints<<<dim3((3 * N + 255) / 256), dim3(256), 0, stream>>>(deg3, 3 * N);
  count_deg<<<dim3((E + 255) / 256), dim3(256), 0, stream>>>(esrc, edst, deg_out, deg_in, E);
  block_sums<<<dim3(nb), dim3(SCAN_BS), 0, stream>>>(deg_in, bsum, N);
  scan_bsums<<<dim3(1), dim3(64), 0, stream>>>(bsum, nb);
  scan_block<<<dim3(nb), dim3(SCAN_BS), 0, stream>>>(deg_in, bsum, row_start, N, E);
  fill_csr<<<dim3((E + 255) / 256), dim3(256), 0, stream>>>(esrc, edst, row_start, cursor, csr_src, E);
  compute_inv<<<dim3((N + 255) / 256), dim3(256), 0, stream>>>(deg_out, deg_in, inv_out, inv_in, N);
  pack_W<<<dim3((L * 2048 + 255) / 256), dim3(256), 0, stream>>>(Ws, Whi, Wlo, L * 2048);
  x_scale_half<<<dim3((N * 64 + 255) / 256), dim3(256), 0, stream>>>(x, inv_out, (__half2*)xh, N);

  float* outf = (float*)d_out;
  const dim3 sgrid((N + 3) / 4), sblk(256);
  const dim3 ggrid(Npad / 64), gblk(256);

  for (int l = 0; l < L; l++) {
    spmm_half<<<sgrid, sblk, 0, stream>>>((const __half2*)xh, row_start, csr_src, inv_in,
                                          (u32*)agg_hi, (u32*)agg_lo, N);
    bool last = (l == L - 1);
    gemm_mfma<<<ggrid, gblk, 0, stream>>>(agg_hi, agg_lo,
                                          Whi + (size_t)l * 16384, Wlo + (size_t)l * 16384,
                                          bs + (size_t)l * D, inv_out,
                                          last ? nullptr : xh, last ? outf : nullptr, N);
  }
}

// Round 5
// 312.510 us; speedup vs baseline: 1.6296x; 1.1611x over previous
//
#include <hip/hip_runtime.h>
#include <hip/hip_fp16.h>

typedef __attribute__((ext_vector_type(8))) _Float16 half8;
typedef __attribute__((ext_vector_type(4))) float f32x4;

#define ELL_PAD 64

// ---------- build: deg_out histogram + ELL fill (cursor = deg_in) + W f16 hi/lo pack ----------
// One kernel: pack work (6144 threads) is independent of the atomic streams and hides their latency.
// Device atomics are fabric-rate-bound (~24 G/s, 32B write-through each) -> minimize their count.

__global__ __launch_bounds__(256) void build(const int* __restrict__ esrc,
                                             const int* __restrict__ edst,
                                             int* __restrict__ deg_out,
                                             int* __restrict__ cursor,
                                             int* __restrict__ ell,
                                             const float* __restrict__ Ws,
                                             _Float16* __restrict__ Whi,
                                             _Float16* __restrict__ Wlo,
                                             int E, int packTotal) {
  int i = blockIdx.x * 256 + threadIdx.x;
  if (i < packTotal) {
    // B-fragment order for mfma_f32_16x16x32_f16:
    // elem j of (layer,ntile,kstep,lane) = W[k=kstep*32+(lane>>4)*8+j][n=ntile*16+(lane&15)]
    int lane  = i & 63;
    int kstep = (i >> 6) & 3;
    int ntile = (i >> 8) & 7;
    int layer = i >> 11;
    int n  = ntile * 16 + (lane & 15);
    int k0 = kstep * 32 + (lane >> 4) * 8;
    const float* W = Ws + (size_t)layer * 128 * 128;
    size_t base = (size_t)i * 8;
    for (int j = 0; j < 8; j++) {
      float v = W[(k0 + j) * 128 + n];
      _Float16 hi = (_Float16)v;
      Whi[base + j] = hi;
      Wlo[base + j] = (_Float16)(v - (float)hi);   // exact residual, |lo| ~ 2^-12|W|
    }
  }
  if (i < E) {
    int s = esrc[i], d = edst[i];
    atomicAdd(&deg_out[s], 1);
    int pos = atomicAdd(&cursor[d], 1);            // cursor ends up = deg_in
    if (pos < ELL_PAD) ell[(size_t)d * ELL_PAD + pos] = s;
  }
}

// ---------- xh[i,:] = fp16( x[i,:] * rsqrt(max(deg_out[i],1)) ) ----------

__global__ __launch_bounds__(256) void xscale(const float* __restrict__ x,
                                              const int* __restrict__ deg_out,
                                              __half2* __restrict__ xh, int n64) {
  int gid = blockIdx.x * 256 + threadIdx.x;
  if (gid >= n64) return;
  int row = gid >> 6;
  int d = deg_out[row]; if (d < 1) d = 1;
  float s = rsqrtf((float)d);
  float2 v = ((const float2*)x)[gid];
  xh[gid] = __floats2half2_rn(v.x * s, v.y * s);
}

// ---------- SpMM (ELL): aggh[i,:] = fp16( rsqrt(max(deg_in,1)) * sum_e xh[src_e,:] ) ----------
// one wave per dst row; lane = half2 (256B/row coalesced); 8 gathers in flight (MLP);
// ELL index reads are wave-uniform int4 loads.

__global__ __launch_bounds__(256) void spmm(const __half2* __restrict__ xh,
                                            const int* __restrict__ cursor,
                                            const int* __restrict__ ell,
                                            __half2* __restrict__ aggh, int n) {
  int row = blockIdx.x * 4 + (threadIdx.x >> 6);
  if (row >= n) return;
  int lane = threadIdx.x & 63;
  int deg = cursor[row];
  if (deg > ELL_PAD) deg = ELL_PAD;
  const int* ep = ell + (size_t)row * ELL_PAD;
  float ax = 0.f, ay = 0.f;
  int e = 0;
  for (; e + 8 <= deg; e += 8) {
    int4 i0 = *(const int4*)&ep[e];
    int4 i1 = *(const int4*)&ep[e + 4];
    __half2 h0 = xh[(size_t)i0.x * 64 + lane];
    __half2 h1 = xh[(size_t)i0.y * 64 + lane];
    __half2 h2 = xh[(size_t)i0.z * 64 + lane];
    __half2 h3 = xh[(size_t)i0.w * 64 + lane];
    __half2 h4 = xh[(size_t)i1.x * 64 + lane];
    __half2 h5 = xh[(size_t)i1.y * 64 + lane];
    __half2 h6 = xh[(size_t)i1.z * 64 + lane];
    __half2 h7 = xh[(size_t)i1.w * 64 + lane];
    float2 v0 = __half22float2(h0), v1 = __half22float2(h1);
    float2 v2 = __half22float2(h2), v3 = __half22float2(h3);
    float2 v4 = __half22float2(h4), v5 = __half22float2(h5);
    float2 v6 = __half22float2(h6), v7 = __half22float2(h7);
    ax += (v0.x + v1.x) + (v2.x + v3.x) + (v4.x + v5.x) + (v6.x + v7.x);
    ay += (v0.y + v1.y) + (v2.y + v3.y) + (v4.y + v5.y) + (v6.y + v7.y);
  }
  for (; e < deg; e++) {
    float2 v = __half22float2(xh[(size_t)ep[e] * 64 + lane]);
    ax += v.x; ay += v.y;
  }
  float si = rsqrtf((float)(deg < 1 ? 1 : deg));
  ax *= si; ay *= si;
  aggh[(size_t)row * 64 + lane] = __floats2half2_rn(ax, ay);
}

// ---------- MFMA GEMM + bias + ReLU (+ rsqrt(deg_out) fold into fp16 output) ----------
// block = 256 (4 waves) -> 64 rows x 128 cols. A = fp16 agg enters f16 MFMA exactly;
// W split f16 hi+lo (residual 2^-22) -> GEMM adds no error beyond agg's fp16 quantization.

__global__ __launch_bounds__(256) void gemm_mfma(const _Float16* __restrict__ A,
                                                 const _Float16* __restrict__ Whi,
                                                 const _Float16* __restrict__ Wlo,
                                                 const float* __restrict__ bias,
                                                 const int* __restrict__ deg_out,
                                                 __half* __restrict__ out16,
                                                 float* __restrict__ out32, int n) {
  __shared__ _Float16 Bh[16384];  // 32 KB
  __shared__ _Float16 Bl[16384];  // 32 KB
  {
    uint4* dh = (uint4*)Bh; const uint4* sh = (const uint4*)Whi;
    uint4* dl = (uint4*)Bl; const uint4* sl = (const uint4*)Wlo;
    for (int i = threadIdx.x; i < 2048; i += 256) { dh[i] = sh[i]; dl[i] = sl[i]; }
  }
  __syncthreads();

  const int wave = threadIdx.x >> 6;
  const int lane = threadIdx.x & 63;
  const int quad = lane >> 4;
  const int l16  = lane & 15;
  const int rowBase = blockIdx.x * 64 + wave * 16;
  const size_t arow = (size_t)(rowBase + l16) * 128;

  f32x4 acc[8];
#pragma unroll
  for (int nt = 0; nt < 8; nt++) acc[nt] = (f32x4){0.f, 0.f, 0.f, 0.f};

#pragma unroll
  for (int ks = 0; ks < 4; ks++) {
    half8 a = *(const half8*)&A[arow + ks * 32 + quad * 8];
#pragma unroll
    for (int nt = 0; nt < 8; nt++) {
      int boff = ((nt * 4 + ks) * 64 + lane) * 8;
      half8 bh = *(const half8*)&Bh[boff];
      half8 bl = *(const half8*)&Bl[boff];
      acc[nt] = __builtin_amdgcn_mfma_f32_16x16x32_f16(a, bh, acc[nt], 0, 0, 0);
      acc[nt] = __builtin_amdgcn_mfma_f32_16x16x32_f16(a, bl, acc[nt], 0, 0, 0);
    }
  }

  // C/D: col = lane&15 (+nt*16), row = quad*4 + reg  [m89-verified mapping]
  const int r0 = rowBase + quad * 4;
  float rs[4];
#pragma unroll
  for (int r = 0; r < 4; r++) {
    if (out16 && (r0 + r) < n) {
      int d = deg_out[r0 + r]; if (d < 1) d = 1;
      rs[r] = rsqrtf((float)d);
    } else rs[r] = 1.0f;
  }
#pragma unroll
  for (int nt = 0; nt < 8; nt++) {
    int col = nt * 16 + l16;
    float bv = bias[col];
#pragma unroll
    for (int r = 0; r < 4; r++) {
      int row = r0 + r;
      if (row < n) {
        float v = fmaxf(acc[nt][r] + bv, 0.f);
        if (out16) out16[(size_t)row * 128 + col] = __float2half(v * rs[r]);
        else       out32[(size_t)row * 128 + col] = v;
      }
    }
  }
}

// ---------- launch ----------

extern "C" void kernel_launch(void* const* d_in, const int* in_sizes, int n_in,
                              void* d_out, int out_size, void* d_ws, size_t ws_size,
                              hipStream_t stream) {
  const float* x   = (const float*)d_in[0];
  const float* Ws  = (const float*)d_in[1];
  const float* bs  = (const float*)d_in[2];
  const int* esrc  = (const int*)d_in[3];
  const int* edst  = (const int*)d_in[4];

  const int D = 128;
  const int N = in_sizes[0] / D;
  const int E = in_sizes[3];
  const int L = in_sizes[1] / (D * D);
  const int Npad = ((N + 63) / 64) * 64;

  // workspace layout, 256B-aligned chunks
  char* base = (char*)d_ws;
  size_t off = 0;
  auto alloc = [&](size_t bytes) {
    char* p = base + off;
    off = (off + bytes + 255) & ~(size_t)255;
    return p;
  };
  // deg_out and cursor contiguous: one memset covers both
  int*      deg2   = (int*)alloc((size_t)2 * N * 4);
  int*      deg_out = deg2;
  int*      cursor  = deg2 + N;
  int*      ell    = (int*)alloc((size_t)N * ELL_PAD * 4);
  _Float16* Whi    = (_Float16*)alloc((size_t)L * 16384 * 2);
  _Float16* Wlo    = (_Float16*)alloc((size_t)L * 16384 * 2);
  _Float16* aggh   = (_Float16*)alloc((size_t)Npad * 128 * 2);
  _Float16* xh     = (_Float16*)alloc((size_t)Npad * 128 * 2);

  hipMemsetAsync(deg2, 0, (size_t)2 * N * 4, stream);
  build<<<dim3((E + 255) / 256), dim3(256), 0, stream>>>(
      esrc, edst, deg_out, cursor, ell, Ws, Whi, Wlo, E, L * 2048);
  xscale<<<dim3((N * 64 + 255) / 256), dim3(256), 0, stream>>>(
      x, deg_out, (__half2*)xh, N * 64);

  float* outf = (float*)d_out;
  const dim3 sgrid((N + 3) / 4), sblk(256);
  const dim3 ggrid(Npad / 64), gblk(256);

  for (int l = 0; l < L; l++) {
    spmm<<<sgrid, sblk, 0, stream>>>((const __half2*)xh, cursor, ell, (__half2*)aggh, N);
    bool last = (l == L - 1);
    gemm_mfma<<<ggrid, gblk, 0, stream>>>(aggh,
                                          Whi + (size_t)l * 16384, Wlo + (size_t)l * 16384,
                                          bs + (size_t)l * D, deg_out,
                                          last ? nullptr : (__half*)xh,
                                          last ? outf : nullptr, N);
  }
}

// Round 6
// 278.128 us; speedup vs baseline: 1.8311x; 1.1236x over previous
//
#include <hip/hip_runtime.h>
#include <hip/hip_fp16.h>

typedef __attribute__((ext_vector_type(8))) _Float16 half8;
typedef __attribute__((ext_vector_type(4))) float f32x4;
typedef unsigned int u32;

#define ELL_PAD 64
#define NCHUNK 128
#define RSZ 8192   // nodes per histogram range (32 KB LDS u32 bins)

// ---------- deg_out histogram: LDS-privatized partials, NO global atomics ----------
// grid = NCHUNK * R blocks; block (c,r) counts srcs in node range r over edge chunk c.
// partial[c*N + node] written coalesced; reduced in hist_reduce.

__global__ __launch_bounds__(256) void hist_part(const int* __restrict__ esrc,
                                                 u32* __restrict__ partial,
                                                 int E, int N, int chunk, int R) {
  __shared__ u32 bins[RSZ];
  int c = blockIdx.x / R;
  int r = blockIdx.x % R;
  int base = r * RSZ;
  if (base >= N) return;
  for (int j = threadIdx.x; j < RSZ; j += 256) bins[j] = 0;
  __syncthreads();
  int e0 = c * chunk;
  int e1 = min(E, e0 + chunk);
  for (int i = e0 + threadIdx.x; i < e1; i += 256) {
    int loc = esrc[i] - base;
    if ((unsigned)loc < (unsigned)RSZ) atomicAdd(&bins[loc], 1u);
  }
  __syncthreads();
  int hi = min(RSZ, N - base);
  u32* dst = partial + (size_t)c * N + base;
  for (int j = threadIdx.x; j < hi; j += 256) dst[j] = bins[j];
}

__global__ __launch_bounds__(256) void hist_reduce(const u32* __restrict__ partial,
                                                   int* __restrict__ deg_out, int N) {
  int i = blockIdx.x * 256 + threadIdx.x;
  if (i >= N) return;
  u32 s = 0;
  for (int c = 0; c < NCHUNK; c++) s += partial[(size_t)c * N + i];
  deg_out[i] = (int)s;
}

// ---------- build: ELL fill (cursor atomic = deg_in) + W f16 hi/lo pack ----------
// 640K device atomics (halved from r5) — the remaining atomic floor.

__global__ __launch_bounds__(256) void build(const int* __restrict__ esrc,
                                             const int* __restrict__ edst,
                                             int* __restrict__ cursor,
                                             int* __restrict__ ell,
                                             const float* __restrict__ Ws,
                                             _Float16* __restrict__ Whi,
                                             _Float16* __restrict__ Wlo,
                                             int E, int packTotal) {
  int i = blockIdx.x * 256 + threadIdx.x;
  if (i < packTotal) {
    // B-fragment order for mfma_f32_16x16x32_f16:
    // elem j of (layer,ntile,kstep,lane) = W[k=kstep*32+(lane>>4)*8+j][n=ntile*16+(lane&15)]
    int lane  = i & 63;
    int kstep = (i >> 6) & 3;
    int ntile = (i >> 8) & 7;
    int layer = i >> 11;
    int n  = ntile * 16 + (lane & 15);
    int k0 = kstep * 32 + (lane >> 4) * 8;
    const float* W = Ws + (size_t)layer * 128 * 128;
    size_t base = (size_t)i * 8;
    for (int j = 0; j < 8; j++) {
      float v = W[(k0 + j) * 128 + n];
      _Float16 hi = (_Float16)v;
      Whi[base + j] = hi;
      Wlo[base + j] = (_Float16)(v - (float)hi);   // exact residual, |lo| ~ 2^-12|W|
    }
  }
  if (i < E) {
    int d = edst[i];
    int pos = atomicAdd(&cursor[d], 1);            // cursor ends up = deg_in
    if (pos < ELL_PAD) ell[(size_t)d * ELL_PAD + pos] = esrc[i];
  }
}

// ---------- xh[i,:] = fp16( x[i,:] * rsqrt(max(deg_out[i],1)) ) ----------

__global__ __launch_bounds__(256) void xscale(const float* __restrict__ x,
                                              const int* __restrict__ deg_out,
                                              __half2* __restrict__ xh, int n64) {
  int gid = blockIdx.x * 256 + threadIdx.x;
  if (gid >= n64) return;
  int row = gid >> 6;
  int d = deg_out[row]; if (d < 1) d = 1;
  float s = rsqrtf((float)d);
  float2 v = ((const float2*)x)[gid];
  xh[gid] = __floats2half2_rn(v.x * s, v.y * s);
}

// ---------- SpMM (ELL): aggh[i,:] = fp16( rsqrt(max(deg_in,1)) * sum_e xh[src_e,:] ) ----------
// one wave per dst row; lane = half2 (256B/row coalesced); 8 gathers in flight, 4-wide mid tier.

__global__ __launch_bounds__(256) void spmm(const __half2* __restrict__ xh,
                                            const int* __restrict__ cursor,
                                            const int* __restrict__ ell,
                                            __half2* __restrict__ aggh, int n) {
  int row = blockIdx.x * 4 + (threadIdx.x >> 6);
  if (row >= n) return;
  int lane = threadIdx.x & 63;
  int deg = cursor[row];
  if (deg > ELL_PAD) deg = ELL_PAD;
  const int* ep = ell + (size_t)row * ELL_PAD;
  float ax = 0.f, ay = 0.f;
  int e = 0;
  for (; e + 8 <= deg; e += 8) {
    int4 i0 = *(const int4*)&ep[e];
    int4 i1 = *(const int4*)&ep[e + 4];
    __half2 h0 = xh[(size_t)i0.x * 64 + lane];
    __half2 h1 = xh[(size_t)i0.y * 64 + lane];
    __half2 h2 = xh[(size_t)i0.z * 64 + lane];
    __half2 h3 = xh[(size_t)i0.w * 64 + lane];
    __half2 h4 = xh[(size_t)i1.x * 64 + lane];
    __half2 h5 = xh[(size_t)i1.y * 64 + lane];
    __half2 h6 = xh[(size_t)i1.z * 64 + lane];
    __half2 h7 = xh[(size_t)i1.w * 64 + lane];
    float2 v0 = __half22float2(h0), v1 = __half22float2(h1);
    float2 v2 = __half22float2(h2), v3 = __half22float2(h3);
    float2 v4 = __half22float2(h4), v5 = __half22float2(h5);
    float2 v6 = __half22float2(h6), v7 = __half22float2(h7);
    ax += (v0.x + v1.x) + (v2.x + v3.x) + (v4.x + v5.x) + (v6.x + v7.x);
    ay += (v0.y + v1.y) + (v2.y + v3.y) + (v4.y + v5.y) + (v6.y + v7.y);
  }
  if (e + 4 <= deg) {
    int4 i0 = *(const int4*)&ep[e];
    __half2 h0 = xh[(size_t)i0.x * 64 + lane];
    __half2 h1 = xh[(size_t)i0.y * 64 + lane];
    __half2 h2 = xh[(size_t)i0.z * 64 + lane];
    __half2 h3 = xh[(size_t)i0.w * 64 + lane];
    float2 v0 = __half22float2(h0), v1 = __half22float2(h1);
    float2 v2 = __half22float2(h2), v3 = __half22float2(h3);
    ax += (v0.x + v1.x) + (v2.x + v3.x);
    ay += (v0.y + v1.y) + (v2.y + v3.y);
    e += 4;
  }
  for (; e < deg; e++) {
    float2 v = __half22float2(xh[(size_t)ep[e] * 64 + lane]);
    ax += v.x; ay += v.y;
  }
  float si = rsqrtf((float)(deg < 1 ? 1 : deg));
  ax *= si; ay *= si;
  aggh[(size_t)row * 64 + lane] = __floats2half2_rn(ax, ay);
}

// ---------- MFMA GEMM + bias + ReLU (+ rsqrt(deg_out) fold into fp16 output) ----------
// block = 512 (8 waves) -> 128 rows x 128 cols; 64 KB LDS -> 2 blocks/CU = 16 waves/CU.
// A = fp16 agg enters f16 MFMA exactly; W split f16 hi+lo (residual 2^-22).

__global__ __launch_bounds__(512) void gemm_mfma(const _Float16* __restrict__ A,
                                                 const _Float16* __restrict__ Whi,
                                                 const _Float16* __restrict__ Wlo,
                                                 const float* __restrict__ bias,
                                                 const int* __restrict__ deg_out,
                                                 __half* __restrict__ out16,
                                                 float* __restrict__ out32, int n) {
  __shared__ _Float16 Bh[16384];  // 32 KB
  __shared__ _Float16 Bl[16384];  // 32 KB
  {
    uint4* dh = (uint4*)Bh; const uint4* sh = (const uint4*)Whi;
    uint4* dl = (uint4*)Bl; const uint4* sl = (const uint4*)Wlo;
    for (int i = threadIdx.x; i < 2048; i += 512) { dh[i] = sh[i]; dl[i] = sl[i]; }
  }
  __syncthreads();

  const int wave = threadIdx.x >> 6;
  const int lane = threadIdx.x & 63;
  const int quad = lane >> 4;
  const int l16  = lane & 15;
  const int rowBase = blockIdx.x * 128 + wave * 16;
  const size_t arow = (size_t)(rowBase + l16) * 128;

  f32x4 acc[8];
#pragma unroll
  for (int nt = 0; nt < 8; nt++) acc[nt] = (f32x4){0.f, 0.f, 0.f, 0.f};

#pragma unroll
  for (int ks = 0; ks < 4; ks++) {
    half8 a = *(const half8*)&A[arow + ks * 32 + quad * 8];
#pragma unroll
    for (int nt = 0; nt < 8; nt++) {
      int boff = ((nt * 4 + ks) * 64 + lane) * 8;
      half8 bh = *(const half8*)&Bh[boff];
      half8 bl = *(const half8*)&Bl[boff];
      acc[nt] = __builtin_amdgcn_mfma_f32_16x16x32_f16(a, bh, acc[nt], 0, 0, 0);
      acc[nt] = __builtin_amdgcn_mfma_f32_16x16x32_f16(a, bl, acc[nt], 0, 0, 0);
    }
  }

  // C/D: col = lane&15 (+nt*16), row = quad*4 + reg  [m89-verified mapping]
  const int r0 = rowBase + quad * 4;
  float rs[4];
#pragma unroll
  for (int r = 0; r < 4; r++) {
    if (out16 && (r0 + r) < n) {
      int d = deg_out[r0 + r]; if (d < 1) d = 1;
      rs[r] = rsqrtf((float)d);
    } else rs[r] = 1.0f;
  }
#pragma unroll
  for (int nt = 0; nt < 8; nt++) {
    int col = nt * 16 + l16;
    float bv = bias[col];
#pragma unroll
    for (int r = 0; r < 4; r++) {
      int row = r0 + r;
      if (row < n) {
        float v = fmaxf(acc[nt][r] + bv, 0.f);
        if (out16) out16[(size_t)row * 128 + col] = __float2half(v * rs[r]);
        else       out32[(size_t)row * 128 + col] = v;
      }
    }
  }
}

// ---------- launch ----------

extern "C" void kernel_launch(void* const* d_in, const int* in_sizes, int n_in,
                              void* d_out, int out_size, void* d_ws, size_t ws_size,
                              hipStream_t stream) {
  const float* x   = (const float*)d_in[0];
  const float* Ws  = (const float*)d_in[1];
  const float* bs  = (const float*)d_in[2];
  const int* esrc  = (const int*)d_in[3];
  const int* edst  = (const int*)d_in[4];

  const int D = 128;
  const int N = in_sizes[0] / D;
  const int E = in_sizes[3];
  const int L = in_sizes[1] / (D * D);
  const int Npad = ((N + 127) / 128) * 128;
  const int chunk = (E + NCHUNK - 1) / NCHUNK;
  const int R = (N + RSZ - 1) / RSZ;

  // workspace layout, 256B-aligned chunks
  char* base = (char*)d_ws;
  size_t off = 0;
  auto alloc = [&](size_t bytes) {
    char* p = base + off;
    off = (off + bytes + 255) & ~(size_t)255;
    return p;
  };
  int*      deg_out = (int*)alloc((size_t)N * 4);
  int*      cursor  = (int*)alloc((size_t)N * 4);
  int*      ell     = (int*)alloc((size_t)N * ELL_PAD * 4);
  _Float16* Whi     = (_Float16*)alloc((size_t)L * 16384 * 2);
  _Float16* Wlo     = (_Float16*)alloc((size_t)L * 16384 * 2);
  _Float16* aggh    = (_Float16*)alloc((size_t)Npad * 128 * 2);
  _Float16* xh      = (_Float16*)alloc((size_t)Npad * 128 * 2);
  // histogram partials alias the (aggh,xh) region: dead after hist_reduce,
  // xh first written by xscale (later), aggh by the first spmm (later still).
  u32*      partial = (u32*)aggh;   // NCHUNK*N*4 = 25.6 MB <= 2*Npad*128*2

  hipMemsetAsync(cursor, 0, (size_t)N * 4, stream);
  hist_part<<<dim3(NCHUNK * R), dim3(256), 0, stream>>>(esrc, partial, E, N, chunk, R);
  hist_reduce<<<dim3((N + 255) / 256), dim3(256), 0, stream>>>(partial, deg_out, N);
  build<<<dim3((E + 255) / 256), dim3(256), 0, stream>>>(
      esrc, edst, cursor, ell, Ws, Whi, Wlo, E, L * 2048);
  xscale<<<dim3((N * 64 + 255) / 256), dim3(256), 0, stream>>>(
      x, deg_out, (__half2*)xh, N * 64);

  float* outf = (float*)d_out;
  const dim3 sgrid((N + 3) / 4), sblk(256);
  const dim3 ggrid(Npad / 128), gblk(512);

  for (int l = 0; l < L; l++) {
    spmm<<<sgrid, sblk, 0, stream>>>((const __half2*)xh, cursor, ell, (__half2*)aggh, N);
    bool last = (l == L - 1);
    gemm_mfma<<<ggrid, gblk, 0, stream>>>(aggh,
                                          Whi + (size_t)l * 16384, Wlo + (size_t)l * 16384,
                                          bs + (size_t)l * D, deg_out,
                                          last ? nullptr : (__half*)xh,
                                          last ? outf : nullptr, N);
  }
}